// Round 11
// baseline (377.904 us; speedup 1.0000x reference)
//
#include <hip/hip_runtime.h>
#include <math.h>

// LSEP loss: loss = log1p( sum_rows (sum_{t==0} exp(x)) * (sum_{t>0} exp(-x)) ) / B
// R11: asm-pipelined. R10 proved loads are probe-identical yet 2x slower than
// the pure-load probe => the dependent compute/barrier phase stalls VMEM issue
// (vmcnt(0) drain every tile, duty cycle ~50%). This version keeps a full
// 6-load prefetch batch in flight across compute+barrier:
//   - loads issued via inline-asm global_load_dwordx4 (can't be collapsed)
//   - consumed after counted s_waitcnt vmcnt(6) + sched_barrier(0)
//   - LDS pairing barrier = raw "lgkmcnt(0); s_barrier" (NO vmcnt drain)
// GRID=3125 -> exactly 5 tiles/block (15625 = 5^6 tiles), hand-unrolled
// ping-pong (A,B,A,B,A), uniform vmcnt counts, no guards anywhere.

constexpr int  ROWS   = 2000000;
constexpr int  BLOCK  = 256;
constexpr int  GRID   = 3125;              // 15625 tiles / 5 per block
constexpr int  TILE4  = 768;               // float4s per tile = 128 rows
constexpr long STEP4  = (long)GRID * TILE4;  // 2,400,000 float4s per stage

typedef float f32x4 __attribute__((ext_vector_type(4)));
typedef int   i32x4 __attribute__((ext_vector_type(4)));

__device__ __forceinline__ float2 pp4(f32x4 x, i32x4 g) {
    float a = 0.0f, b = 0.0f;
    #pragma unroll
    for (int j = 0; j < 4; ++j) {
        const float e = __expf(__int_as_float(__float_as_int(x[j]) ^ (g[j] << 31)));
        const float f = (float)g[j];
        b = fmaf(e, f, b);
        a = fmaf(e, 1.0f - f, a);
    }
    return make_float2(a, b);
}

#define ISSUE(X, G, B4) do {                                                              \
    const f32x4* pf_ = fin + (B4) + t;                                                    \
    const i32x4* pg_ = gin + (B4) + t;                                                    \
    asm volatile("global_load_dwordx4 %0, %1, off" : "=v"(X[0]) : "v"(pf_)       : "memory"); \
    asm volatile("global_load_dwordx4 %0, %1, off" : "=v"(X[1]) : "v"(pf_ + 256) : "memory"); \
    asm volatile("global_load_dwordx4 %0, %1, off" : "=v"(X[2]) : "v"(pf_ + 512) : "memory"); \
    asm volatile("global_load_dwordx4 %0, %1, off" : "=v"(G[0]) : "v"(pg_)       : "memory"); \
    asm volatile("global_load_dwordx4 %0, %1, off" : "=v"(G[1]) : "v"(pg_ + 256) : "memory"); \
    asm volatile("global_load_dwordx4 %0, %1, off" : "=v"(G[2]) : "v"(pg_ + 512) : "memory"); \
} while (0)

#define WAITV(N) do {                                                 \
    asm volatile("s_waitcnt vmcnt(" #N ")" ::: "memory");             \
    __builtin_amdgcn_sched_barrier(0);                                \
} while (0)

// raw barrier: LDS visibility only, vmcnt (prefetch) stays outstanding
#define LDS_BARRIER() asm volatile("s_waitcnt lgkmcnt(0)\n\ts_barrier" ::: "memory")

#define COMPUTE(X, G, BUF) do {                                                      \
    const float2 p0_ = pp4(X[0], G[0]);                                              \
    const float2 p1_ = pp4(X[1], G[1]);                                              \
    const float2 p2_ = pp4(X[2], G[2]);                                              \
    pair[BUF][t]       = p0_;                                                        \
    pair[BUF][t + 256] = p1_;                                                        \
    pair[BUF][t + 512] = p2_;                                                        \
    LDS_BARRIER();                                                                   \
    if (t < 128) {                                                                   \
        const float4* pr_ = reinterpret_cast<const float4*>(&pair[BUF][0]) + 3 * t;  \
        const float4 q0_ = pr_[0], q1_ = pr_[1], q2_ = pr_[2];                       \
        const float a_ = (q0_.x + q0_.z) + (q1_.x + q1_.z) + (q2_.x + q2_.z);        \
        const float b_ = (q0_.y + q0_.w) + (q1_.y + q1_.w) + (q2_.y + q2_.w);        \
        acc += (double)a_ * (double)b_;                                              \
    }                                                                                \
} while (0)

__global__ __launch_bounds__(BLOCK) void lsep_main(
        const f32x4* __restrict__ fin,
        const i32x4* __restrict__ gin,
        double*      __restrict__ partials)
{
    __shared__ __align__(16) float2 pair[2][TILE4];   // double buffer, 12 KB
    __shared__ double sred[BLOCK / 64];

    const int  t  = threadIdx.x;
    const long b0 = (long)blockIdx.x * TILE4;
    double acc = 0.0;

    f32x4 XA[3], XB[3];
    i32x4 GA[3], GB[3];

    // prologue: tile 0 in flight
    ISSUE(XA, GA, b0);

    // stage 0..4: ping-pong A,B,A,B,A; prefetch next while computing current
    ISSUE(XB, GB, b0 + 1 * STEP4);  WAITV(6);  COMPUTE(XA, GA, 0);
    ISSUE(XA, GA, b0 + 2 * STEP4);  WAITV(6);  COMPUTE(XB, GB, 1);
    ISSUE(XB, GB, b0 + 3 * STEP4);  WAITV(6);  COMPUTE(XA, GA, 0);
    ISSUE(XA, GA, b0 + 4 * STEP4);  WAITV(6);  COMPUTE(XB, GB, 1);
    /* no prefetch */               WAITV(0);  COMPUTE(XA, GA, 0);

    // ---- block reduction (f64) ----
    #pragma unroll
    for (int off = 32; off > 0; off >>= 1)
        acc += __shfl_down(acc, off, 64);
    if ((t & 63) == 0) sred[t >> 6] = acc;
    __syncthreads();
    if (t == 0)
        partials[blockIdx.x] = (sred[0] + sred[1]) + (sred[2] + sred[3]);
}

__global__ void lsep_finalize(const double* __restrict__ partials,
                              float* __restrict__ out)
{
    __shared__ double sred[4];
    const int t = threadIdx.x;
    double s = 0.0;
    for (int i = t; i < GRID; i += 256) s += partials[i];
    #pragma unroll
    for (int off = 32; off > 0; off >>= 1)
        s += __shfl_down(s, off, 64);
    if ((t & 63) == 0) sred[t >> 6] = s;
    __syncthreads();
    if (t == 0)
        out[0] = (float)(log1p((sred[0] + sred[1]) + (sred[2] + sred[3])) / (double)ROWS);
}

extern "C" void kernel_launch(void* const* d_in, const int* in_sizes, int n_in,
                              void* d_out, int out_size, void* d_ws, size_t ws_size,
                              hipStream_t stream) {
    const f32x4* fin = (const f32x4*)d_in[0];
    const i32x4* gin = (const i32x4*)d_in[1];
    double* partials = (double*)d_ws;      // 3125 f64 = 25 KB
    float*  out      = (float*)d_out;

    lsep_main<<<GRID, BLOCK, 0, stream>>>(fin, gin, partials);
    lsep_finalize<<<1, 256, 0, stream>>>(partials, out);
}